// Round 5
// baseline (322.562 us; speedup 1.0000x reference)
//
#include <hip/hip_runtime.h>

// ---------------------------------------------------------------------------
// LSTransformerEncoderLayer on MI355X (gfx950), round 4.
// Round-4 change: ALL GEMMs -> gemm_dp: BM=128 x BN=256, 8 waves (2Mx4N),
// wave tile 64x64, ONE 32-MFMA phase per K-tile (fragments read once:
// 16 b128/wave/K-tile), 2 barriers/K-tile, 3-slot LDS ring (144KB) staged
// 2 tiles ahead, vmcnt(6) counted wait. Exact grid multiples of 256 CUs for
// every GEMM (768/1024/256/256). attn/LN/wconv unchanged from round 1.
// ---------------------------------------------------------------------------

using f32x4  = __attribute__((ext_vector_type(4))) float;
using f32x16 = __attribute__((ext_vector_type(16))) float;
using s16x8  = __attribute__((ext_vector_type(8))) short;   // 8 bf16 in 4 VGPRs
using i32x4  = __attribute__((ext_vector_type(4))) int;

__device__ __forceinline__ unsigned short f2bf(float f) {
    unsigned x = __builtin_bit_cast(unsigned, f);
    return (unsigned short)((x + 0x7fffu + ((x >> 16) & 1u)) >> 16);  // RNE
}

#define GLL16(gptr, lptr)                                                     \
    __builtin_amdgcn_global_load_lds(                                         \
        (const __attribute__((address_space(1))) void*)(gptr),                \
        (__attribute__((address_space(3))) void*)(lptr), 16, 0, 0)

#define VMC(N) asm volatile("s_waitcnt vmcnt(" #N ")" ::: "memory")

// ---------------------------------------------------------------------------
// Weight convert: fp32 -> bf16, all four weights in one launch.
// ---------------------------------------------------------------------------
__global__ __launch_bounds__(256) void wconv_kernel(
    const float* __restrict__ w0, const float* __restrict__ w1,
    const float* __restrict__ w2, const float* __restrict__ w3,
    unsigned short* __restrict__ o0, unsigned short* __restrict__ o1,
    unsigned short* __restrict__ o2, unsigned short* __restrict__ o3) {
    long idx = (long)blockIdx.x * 256 + threadIdx.x;  // float4 index
    const float* src;
    unsigned short* dst;
    long rel;
    if (idx < 786432L)        { src = w0; dst = o0; rel = idx; }
    else if (idx < 1048576L)  { src = w1; dst = o1; rel = idx - 786432L; }
    else if (idx < 2097152L)  { src = w2; dst = o2; rel = idx - 1048576L; }
    else                      { src = w3; dst = o3; rel = idx - 2097152L; }
    float4 v = *(const float4*)(src + rel * 4);
    ushort4 o;
    o.x = f2bf(v.x); o.y = f2bf(v.y); o.z = f2bf(v.z); o.w = f2bf(v.w);
    *(ushort4*)(dst + rel * 4) = o;
}

// ---------------------------------------------------------------------------
// LayerNorm: one block per row of 1024 fp32, 256 threads (one float4 each).
// ---------------------------------------------------------------------------
__global__ __launch_bounds__(256) void ln_kernel(
    const float* __restrict__ x, const float* __restrict__ gw,
    const float* __restrict__ bw, unsigned short* __restrict__ y) {
    __shared__ float rbuf[8];
    const int row = blockIdx.x;
    const int t = threadIdx.x;
    const float* xr = x + (size_t)row * 1024;
    float4 v = *(const float4*)(xr + t * 4);
    float s  = v.x + v.y + v.z + v.w;
    float ss = v.x * v.x + v.y * v.y + v.z * v.z + v.w * v.w;
#pragma unroll
    for (int sh = 1; sh < 64; sh <<= 1) {
        s  += __shfl_xor(s, sh, 64);
        ss += __shfl_xor(ss, sh, 64);
    }
    int w = t >> 6;
    if ((t & 63) == 0) { rbuf[w * 2] = s; rbuf[w * 2 + 1] = ss; }
    __syncthreads();
    s  = rbuf[0] + rbuf[2] + rbuf[4] + rbuf[6];
    ss = rbuf[1] + rbuf[3] + rbuf[5] + rbuf[7];
    float mu  = s * (1.f / 1024.f);
    float var = ss * (1.f / 1024.f) - mu * mu;
    float rs  = rsqrtf(var + 1e-5f);
    float4 gv = *(const float4*)(gw + t * 4);
    float4 bv = *(const float4*)(bw + t * 4);
    ushort4 o;
    o.x = f2bf((v.x - mu) * rs * gv.x + bv.x);
    o.y = f2bf((v.y - mu) * rs * gv.y + bv.y);
    o.z = f2bf((v.z - mu) * rs * gv.z + bv.z);
    o.w = f2bf((v.w - mu) * rs * gv.w + bv.w);
    *(ushort4*)(y + (size_t)row * 1024 + t * 4) = o;
}

// ---------------------------------------------------------------------------
// gemm_dp: C[M,N] = A[M,K]*B[N,K]^T (+bias, +resid, relu, bf16/f32 out).
// BM=128, BN=256, BK=64. 512 thr = 8 waves (2M x 4N), wave tile 64x64,
// acc[4][4] f32x4, af/bf read ONCE per K-tile (16 b128/wave), one 32-MFMA
// cluster, 2 barriers per K-tile.
// LDS: 3-slot ring, slot = 48KB {A[128][64]bf16 @0, B[256][64]bf16 @16384},
// XOR-swizzle ((row&7)<<4) via pre-swizzled GLL source + swizzled ds_read.
// Staging: full tile t+2 issued at tile t (6 GLL/thread). vmcnt(6) drains
// stage(t+1) (issued one tile earlier -> HBM latency hidden). Tails:
// t+2==NT -> vmcnt(0); t+1==NT -> no wait. Prologue: stage(0),stage(1),
// vmcnt(6) drains stage(0). Write-after-read: slot (t+2)%3 was last read at
// tile t-1, whose reads completed before t-1's MFMA (lgkmcnt) and the
// end-of-(t-1) barrier precedes this GLL issue.
// ---------------------------------------------------------------------------
template <bool RELU, bool RESID, bool OUT_BF16>
__global__ __launch_bounds__(512, 2) void gemm_dp(
    const unsigned short* __restrict__ A, const unsigned short* __restrict__ Bw,
    const float* __restrict__ bias, const float* __restrict__ resid,
    void* __restrict__ Cout, int M, int N, int K) {
    extern __shared__ char lds[];

    const int tid = threadIdx.x;
    const int lane = tid & 63;
    const int w = tid >> 6;
    const int wm = w >> 2, wn = w & 3;   // 2M x 4N
    const int g = lane >> 4, fr = lane & 15;

    // T1 bijective XCD swizzle (all grids have nwg % 8 == 0)
    const int nwg = gridDim.x * gridDim.y;
    const int L = blockIdx.y * gridDim.x + blockIdx.x;
    const int swz = (L & 7) * (nwg >> 3) + (L >> 3);
    const int m0 = (swz / gridDim.x) * 128;
    const int n0 = (swz % gridDim.x) * 256;

    const int NT = K >> 6;   // NT >= 2 required (here 16 or 64)

    auto stage = [&](int t) {
        char* dst = lds + (t % 3) * 49152;
#pragma unroll
        for (int c = 0; c < 2; ++c) {   // A: 128x64 bf16 = 16KB
            int lin = (c * 512 + tid) * 16;
            int row = lin >> 7;
            int colb = (lin & 127) ^ ((row & 7) << 4);
            GLL16((const char*)A + ((size_t)(m0 + row) * K + t * 64) * 2 + colb,
                  dst + lin);
        }
#pragma unroll
        for (int c = 0; c < 4; ++c) {   // B: 256x64 bf16 = 32KB
            int lin = (c * 512 + tid) * 16;
            int row = lin >> 7;
            int colb = (lin & 127) ^ ((row & 7) << 4);
            GLL16((const char*)Bw + ((size_t)(n0 + row) * K + t * 64) * 2 + colb,
                  dst + 16384 + lin);
        }
    };

    f32x4 acc[4][4] = {};   // [mi][ni]

    stage(0);
    stage(1);
    VMC(6);                  // drain stage(0), leave stage(1) in flight
    __builtin_amdgcn_s_barrier();

    for (int t = 0; t < NT; ++t) {
        char* Ab = lds + (t % 3) * 49152;
        char* Bb = Ab + 16384;
        s16x8 af[4][2], bf[4][2];
#pragma unroll
        for (int mi = 0; mi < 4; ++mi) {
            int row = wm * 64 + mi * 16 + fr;
#pragma unroll
            for (int ks = 0; ks < 2; ++ks)
                af[mi][ks] = *(const s16x8*)(Ab + (row << 7) +
                              ((ks * 64 + g * 16) ^ ((row & 7) << 4)));
        }
#pragma unroll
        for (int ni = 0; ni < 4; ++ni) {
            int row = wn * 64 + ni * 16 + fr;
#pragma unroll
            for (int ks = 0; ks < 2; ++ks)
                bf[ni][ks] = *(const s16x8*)(Bb + (row << 7) +
                              ((ks * 64 + g * 16) ^ ((row & 7) << 4)));
        }
        if (t + 2 < NT) { stage(t + 2); VMC(6); }   // drain stage(t+1)
        else if (t + 1 < NT) { VMC(0); }            // drain stage(NT-1)
        __builtin_amdgcn_s_barrier();
        asm volatile("s_waitcnt lgkmcnt(0)" ::: "memory");
        __builtin_amdgcn_sched_barrier(0);
        __builtin_amdgcn_s_setprio(1);
#pragma unroll
        for (int mi = 0; mi < 4; ++mi)
#pragma unroll
            for (int ni = 0; ni < 4; ++ni)
#pragma unroll
                for (int ks = 0; ks < 2; ++ks)
                    acc[mi][ni] = __builtin_amdgcn_mfma_f32_16x16x32_bf16(
                        af[mi][ks], bf[ni][ks], acc[mi][ni], 0, 0, 0);
        __builtin_amdgcn_s_setprio(0);
        __builtin_amdgcn_s_barrier();
    }

    // epilogue: bias (+relu) (+resid), store
    float bv[4];
#pragma unroll
    for (int ni = 0; ni < 4; ++ni) bv[ni] = bias[n0 + wn * 64 + ni * 16 + fr];
#pragma unroll
    for (int mi = 0; mi < 4; ++mi) {
#pragma unroll
        for (int r = 0; r < 4; ++r) {
            int row = m0 + wm * 64 + mi * 16 + g * 4 + r;
#pragma unroll
            for (int ni = 0; ni < 4; ++ni) {
                int col = n0 + wn * 64 + ni * 16 + fr;
                float v = acc[mi][ni][r] + bv[ni];
                if (RELU) v = v > 0.f ? v : 0.f;
                if (RESID) v += resid[(size_t)row * N + col];
                if (OUT_BF16)
                    ((unsigned short*)Cout)[(size_t)row * N + col] = f2bf(v);
                else
                    ((float*)Cout)[(size_t)row * N + col] = v;
            }
        }
    }
}

// ---------------------------------------------------------------------------
// Fused attention v2 (unchanged from round 1).
// ---------------------------------------------------------------------------
__global__ __launch_bounds__(512, 2) void attn_kernel(
    const unsigned short* __restrict__ qkv, const float* __restrict__ mask,
    unsigned short* __restrict__ ctx) {
    extern __shared__ char smem[];

    const int tid = threadIdx.x;
    const int lane = tid & 63;
    const int w = tid >> 6;
    const int l31 = lane & 31;
    const int hi = lane >> 5;
    const int bh = blockIdx.x >> 1;
    const int b = bh >> 4, h = bh & 15;
    const int qt = (blockIdx.x & 1) * 256 + w * 32;

    const size_t rstr = 3072;
    const unsigned short* qbase = qkv + (size_t)b * 512 * rstr + h * 64;
    const unsigned short* kbase = qbase + 1024;
    const unsigned short* vbase = qbase + 2048;
    const float* mrow = mask + b * 512;

    s16x8 qf[4];
#pragma unroll
    for (int kc = 0; kc < 4; ++kc)
        qf[kc] = *(const s16x8*)(qbase + (size_t)(qt + l31) * rstr + kc * 16 + hi * 8);

    f32x16 O0 = {}, O1 = {};
    float m = -3e38f, l = 0.f;
    const int bpbase = 36 * hi * 4;

    auto stage = [&](int kt, int bufsel) {
        char* Kb = smem + bufsel * 16384;
        char* Vb = smem + 32768 + bufsel * 16384;
#pragma unroll
        for (int c = 0; c < 2; ++c) {
            int lin = (c * 512 + tid) * 16;
            int row = lin >> 7;
            int colb = (lin & 127) ^ ((row & 7) << 4);
            GLL16((const char*)kbase + (size_t)(kt * 128 + row) * rstr * 2 + colb,
                  Kb + lin);
        }
        int s = tid & 127, dg = tid >> 7;
        const unsigned short* vsrc = vbase + (size_t)(kt * 128 + s) * rstr + dg * 16;
        union { i32x4 v; unsigned short u[8]; } v0, v1;
        v0.v = *(const i32x4*)vsrc;
        v1.v = *(const i32x4*)(vsrc + 8);
#pragma unroll
        for (int j = 0; j < 8; ++j) {
            int d = dg * 16 + j;
            *(unsigned short*)(Vb + d * 256 + ((s * 2) ^ ((d & 15) << 4))) = v0.u[j];
        }
#pragma unroll
        for (int j = 0; j < 8; ++j) {
            int d = dg * 16 + 8 + j;
            *(unsigned short*)(Vb + d * 256 + ((s * 2) ^ ((d & 15) << 4))) = v1.u[j];
        }
    };

    const float C   = 0.18033688f;   // log2e / sqrt(64)
    const float L2E = 1.44269504f;

    stage(0, 0);
    __syncthreads();

    for (int kt = 0; kt < 4; ++kt) {
        const int cur = kt & 1;
        if (kt < 3) stage(kt + 1, cur ^ 1);
        char* Kb = smem + cur * 16384;
        char* Vb = smem + 32768 + cur * 16384;
        const int swzk = (l31 & 7) << 4;

        f32x16 sc[4];
#pragma unroll
        for (int t = 0; t < 4; ++t) {
            f32x16 a = {};
#pragma unroll
            for (int kc = 0; kc < 4; ++kc) {
                s16x8 kf = *(const s16x8*)(Kb + (32 * t + l31) * 128 +
                                           ((kc * 32 + hi * 16) ^ swzk));
                a = __builtin_amdgcn_mfma_f32_32x32x16_bf16(kf, qf[kc], a, 0, 0, 0);
            }
            sc[t] = a;
        }

        float tm = -3e38f;
#pragma unroll
        for (int t = 0; t < 4; ++t) {
#pragma unroll
            for (int k2 = 0; k2 < 4; ++k2) {
                f32x4 mk = *(const f32x4*)(mrow + kt * 128 + 32 * t + 8 * k2 + 4 * hi);
#pragma unroll
                for (int i = 0; i < 4; ++i) {
                    float v = sc[t][4 * k2 + i] * C + mk[i] * L2E;
                    sc[t][4 * k2 + i] = v;
                    tm = fmaxf(tm, v);
                }
            }
        }
        tm = fmaxf(tm, __shfl_xor(tm, 32, 64));

        if (__any(tm > m + 11.0f)) {
            float mn = fmaxf(m, tm);
            float fac = exp2f(m - mn);
            m = mn;
            l *= fac;
            int fi = __float_as_int(fac);
#pragma unroll
            for (int r = 0; r < 16; ++r) {
                int q2 = (r & 3) + 8 * (r >> 2);
                float fq = __int_as_float(
                    __builtin_amdgcn_ds_bpermute(bpbase + q2 * 4, fi));
                O0[r] *= fq;
                O1[r] *= fq;
            }
        }

        float ts = 0.f;
#pragma unroll
        for (int t = 0; t < 4; ++t)
#pragma unroll
            for (int r = 0; r < 16; ++r) {
                float p = exp2f(sc[t][r] - m);
                sc[t][r] = p;
                ts += p;
            }
        ts += __shfl_xor(ts, 32, 64);
        l += ts;

        unsigned pk01[4][4], pk23[4][4];
#pragma unroll
        for (int t = 0; t < 4; ++t)
#pragma unroll
            for (int k = 0; k < 4; ++k) {
                unsigned r0, r1;
                asm("v_cvt_pk_bf16_f32 %0, %1, %2"
                    : "=v"(r0) : "v"(sc[t][4 * k]), "v"(sc[t][4 * k + 1]));
                asm("v_cvt_pk_bf16_f32 %0, %1, %2"
                    : "=v"(r1) : "v"(sc[t][4 * k + 2]), "v"(sc[t][4 * k + 3]));
                pk01[t][k] = r0;
                pk23[t][k] = r1;
            }

#pragma unroll
        for (int t = 0; t < 4; ++t)
#pragma unroll
            for (int cc = 0; cc < 2; ++cc) {
                unsigned a0 = pk01[t][2 * cc], b0 = pk01[t][2 * cc + 1];
                unsigned c0 = pk23[t][2 * cc], d0 = pk23[t][2 * cc + 1];
                asm("v_permlane32_swap_b32 %0, %1" : "+v"(a0), "+v"(b0));
                asm("v_permlane32_swap_b32 %0, %1" : "+v"(c0), "+v"(d0));
                union { unsigned u[4]; s16x8 v; } pf;
                pf.u[0] = a0;
                pf.u[1] = c0;
                pf.u[2] = b0;
                pf.u[3] = d0;
                const int kc = 2 * t + cc;
                {
                    int row = l31;
                    s16x8 vf = *(const s16x8*)(Vb + row * 256 +
                               ((kc * 32 + hi * 16) ^ ((row & 15) << 4)));
                    O0 = __builtin_amdgcn_mfma_f32_32x32x16_bf16(pf.v, vf, O0, 0, 0, 0);
                }
                {
                    int row = 32 + l31;
                    s16x8 vf = *(const s16x8*)(Vb + row * 256 +
                               ((kc * 32 + hi * 16) ^ ((row & 15) << 4)));
                    O1 = __builtin_amdgcn_mfma_f32_32x32x16_bf16(pf.v, vf, O1, 0, 0, 0);
                }
            }
        __syncthreads();
    }

    const int li = __float_as_int(l);
#pragma unroll
    for (int r = 0; r < 16; ++r) {
        int q2 = (r & 3) + 8 * (r >> 2);
        float lq = __int_as_float(__builtin_amdgcn_ds_bpermute(bpbase + q2 * 4, li));
        float inv = 1.f / lq;
        size_t rowg = (size_t)(b * 512 + qt + q2 + 4 * hi) * 1024 + h * 64;
        ctx[rowg + l31]      = f2bf(O0[r] * inv);
        ctx[rowg + 32 + l31] = f2bf(O1[r] * inv);
    }
}

// ---------------------------------------------------------------------------
// Launch. ws layout (bytes): see round-0 comment (unchanged).
// ---------------------------------------------------------------------------
extern "C" void kernel_launch(void* const* d_in, const int* in_sizes, int n_in,
                              void* d_out, int out_size, void* d_ws, size_t ws_size,
                              hipStream_t stream) {
    const float* x    = (const float*)d_in[0];
    const float* mask = (const float*)d_in[1];
    const float* qkvw = (const float*)d_in[2];
    const float* qkvb = (const float*)d_in[3];
    const float* ow   = (const float*)d_in[4];
    const float* ob   = (const float*)d_in[5];
    const float* ln1g = (const float*)d_in[6];
    const float* ln1b = (const float*)d_in[7];
    const float* iw   = (const float*)d_in[8];
    const float* ib   = (const float*)d_in[9];
    const float* o2w  = (const float*)d_in[10];
    const float* o2b  = (const float*)d_in[11];
    const float* ln2g = (const float*)d_in[12];
    const float* ln2b = (const float*)d_in[13];

    char* ws = (char*)d_ws;
    unsigned short* qkvbuf = (unsigned short*)(ws);
    unsigned short* ybuf   = (unsigned short*)(ws + 50331648);
    unsigned short* cbuf   = (unsigned short*)(ws + 67108864);
    float*          x2     = (float*)(ws + 83886080);
    unsigned short* wq     = (unsigned short*)(ws + 117440512);
    unsigned short* wo     = (unsigned short*)(ws + 123731968);
    unsigned short* wi     = (unsigned short*)(ws + 125829120);
    unsigned short* wo2    = (unsigned short*)(ws + 134217728);
    unsigned short* hbuf   = (unsigned short*)(ws);  // overlays qkvbuf+ybuf

    hipFuncSetAttribute(reinterpret_cast<const void*>(attn_kernel),
                        hipFuncAttributeMaxDynamicSharedMemorySize, 65536);
    hipFuncSetAttribute(reinterpret_cast<const void*>(&gemm_dp<false, false, true>),
                        hipFuncAttributeMaxDynamicSharedMemorySize, 147456);
    hipFuncSetAttribute(reinterpret_cast<const void*>(&gemm_dp<false, true, false>),
                        hipFuncAttributeMaxDynamicSharedMemorySize, 147456);
    hipFuncSetAttribute(reinterpret_cast<const void*>(&gemm_dp<true, false, true>),
                        hipFuncAttributeMaxDynamicSharedMemorySize, 147456);

    wconv_kernel<<<12288, 256, 0, stream>>>(qkvw, ow, iw, o2w, wq, wo, wi, wo2);
    ln_kernel<<<8192, 256, 0, stream>>>(x, ln1g, ln1b, ybuf);
    gemm_dp<false, false, true><<<dim3(12, 64), 512, 147456, stream>>>(
        ybuf, wq, qkvb, nullptr, qkvbuf, 8192, 3072, 1024);
    attn_kernel<<<512, 512, 65536, stream>>>(qkvbuf, mask, cbuf);
    gemm_dp<false, true, false><<<dim3(4, 64), 512, 147456, stream>>>(
        cbuf, wo, ob, x, x2, 8192, 1024, 1024);
    ln_kernel<<<8192, 256, 0, stream>>>(x2, ln2g, ln2b, cbuf);
    gemm_dp<true, false, true><<<dim3(16, 64), 512, 147456, stream>>>(
        cbuf, wi, ib, nullptr, hbuf, 8192, 4096, 1024);
    gemm_dp<false, true, false><<<dim3(4, 64), 512, 147456, stream>>>(
        hbuf, wo2, o2b, x2, (float*)d_out, 8192, 1024, 4096);
}

// Round 6
// 305.533 us; speedup vs baseline: 1.0557x; 1.0557x over previous
//
#include <hip/hip_runtime.h>

// ---------------------------------------------------------------------------
// LSTransformerEncoderLayer on MI355X (gfx950), round 5.
// Consolidation: per-shape measured-best GEMM configs —
//   QKV  = gemm_dp  (128x256, 768 blocks = 3 clean rounds)   [r4-measured]
//   FFN1 = gemm256  (256x256 8-phase, 512 blocks = 2 rounds) [r3-measured]
//   proj/FFN2 = gemm_bt (128x128, 2 blk/CU)                  [r3-measured]
// K=1024 GEMMs are at the documented plain-HIP ceiling (~860 TF, m248).
// attn: T14 async-STAGE split (issue V/K loads for kt+1 before QK^T(kt),
// scatter-write after softmax). LN/wconv unchanged (HBM ceiling).
// ---------------------------------------------------------------------------

using f32x4  = __attribute__((ext_vector_type(4))) float;
using f32x16 = __attribute__((ext_vector_type(16))) float;
using s16x8  = __attribute__((ext_vector_type(8))) short;   // 8 bf16 in 4 VGPRs
using i32x4  = __attribute__((ext_vector_type(4))) int;

__device__ __forceinline__ unsigned short f2bf(float f) {
    unsigned x = __builtin_bit_cast(unsigned, f);
    return (unsigned short)((x + 0x7fffu + ((x >> 16) & 1u)) >> 16);  // RNE
}

#define GLL16(gptr, lptr)                                                     \
    __builtin_amdgcn_global_load_lds(                                         \
        (const __attribute__((address_space(1))) void*)(gptr),                \
        (__attribute__((address_space(3))) void*)(lptr), 16, 0, 0)

#define VMC(N) asm volatile("s_waitcnt vmcnt(" #N ")" ::: "memory")

// ---------------------------------------------------------------------------
// Weight convert: fp32 -> bf16, all four weights in one launch.
// ---------------------------------------------------------------------------
__global__ __launch_bounds__(256) void wconv_kernel(
    const float* __restrict__ w0, const float* __restrict__ w1,
    const float* __restrict__ w2, const float* __restrict__ w3,
    unsigned short* __restrict__ o0, unsigned short* __restrict__ o1,
    unsigned short* __restrict__ o2, unsigned short* __restrict__ o3) {
    long idx = (long)blockIdx.x * 256 + threadIdx.x;  // float4 index
    const float* src;
    unsigned short* dst;
    long rel;
    if (idx < 786432L)        { src = w0; dst = o0; rel = idx; }
    else if (idx < 1048576L)  { src = w1; dst = o1; rel = idx - 786432L; }
    else if (idx < 2097152L)  { src = w2; dst = o2; rel = idx - 1048576L; }
    else                      { src = w3; dst = o3; rel = idx - 2097152L; }
    float4 v = *(const float4*)(src + rel * 4);
    ushort4 o;
    o.x = f2bf(v.x); o.y = f2bf(v.y); o.z = f2bf(v.z); o.w = f2bf(v.w);
    *(ushort4*)(dst + rel * 4) = o;
}

// ---------------------------------------------------------------------------
// LayerNorm: one block per row of 1024 fp32, 256 threads (one float4 each).
// ---------------------------------------------------------------------------
__global__ __launch_bounds__(256) void ln_kernel(
    const float* __restrict__ x, const float* __restrict__ gw,
    const float* __restrict__ bw, unsigned short* __restrict__ y) {
    __shared__ float rbuf[8];
    const int row = blockIdx.x;
    const int t = threadIdx.x;
    const float* xr = x + (size_t)row * 1024;
    float4 v = *(const float4*)(xr + t * 4);
    float s  = v.x + v.y + v.z + v.w;
    float ss = v.x * v.x + v.y * v.y + v.z * v.z + v.w * v.w;
#pragma unroll
    for (int sh = 1; sh < 64; sh <<= 1) {
        s  += __shfl_xor(s, sh, 64);
        ss += __shfl_xor(ss, sh, 64);
    }
    int w = t >> 6;
    if ((t & 63) == 0) { rbuf[w * 2] = s; rbuf[w * 2 + 1] = ss; }
    __syncthreads();
    s  = rbuf[0] + rbuf[2] + rbuf[4] + rbuf[6];
    ss = rbuf[1] + rbuf[3] + rbuf[5] + rbuf[7];
    float mu  = s * (1.f / 1024.f);
    float var = ss * (1.f / 1024.f) - mu * mu;
    float rs  = rsqrtf(var + 1e-5f);
    float4 gv = *(const float4*)(gw + t * 4);
    float4 bv = *(const float4*)(bw + t * 4);
    ushort4 o;
    o.x = f2bf((v.x - mu) * rs * gv.x + bv.x);
    o.y = f2bf((v.y - mu) * rs * gv.y + bv.y);
    o.z = f2bf((v.z - mu) * rs * gv.z + bv.z);
    o.w = f2bf((v.w - mu) * rs * gv.w + bv.w);
    *(ushort4*)(y + (size_t)row * 1024 + t * 4) = o;
}

// ---------------------------------------------------------------------------
// gemm_bt (m97 2-barrier structure) + T1 XCD swizzle. Used for proj & FFN2.
// ---------------------------------------------------------------------------
template <bool RELU, bool RESID, bool OUT_BF16>
__global__ __launch_bounds__(256, 2) void gemm_bt(
    const unsigned short* __restrict__ A, const unsigned short* __restrict__ Bw,
    const float* __restrict__ bias, const float* __restrict__ resid,
    void* __restrict__ Cout, int M, int N, int K) {
    __shared__ char smem[2 * 128 * 64 * 2];
    char* As = smem;
    char* Bs = smem + 128 * 64 * 2;

    const int tid = threadIdx.x;
    const int lane = tid & 63;
    const int w = tid >> 6;
    const int wr = w >> 1, wc = w & 1;
    const int g = lane >> 4;
    const int fr = lane & 15;
    const int nwg = gridDim.x * gridDim.y;
    const int L = blockIdx.y * gridDim.x + blockIdx.x;
    const int swz = (L & 7) * (nwg >> 3) + (L >> 3);
    const int m0 = (swz / gridDim.x) * 128;
    const int n0 = (swz % gridDim.x) * 128;

    f32x4 acc[4][4] = {};

    for (int kt = 0; kt < K; kt += 64) {
#pragma unroll
        for (int c = 0; c < 4; ++c) {
            int lin = (c * 256 + tid) * 16;
            int row = lin >> 7;
            int Lb = lin ^ ((row & 7) << 4);
            int colb = Lb & 127;
            const char* ga = (const char*)A + ((size_t)(m0 + row) * K + kt) * 2 + colb;
            const char* gb = (const char*)Bw + ((size_t)(n0 + row) * K + kt) * 2 + colb;
            GLL16(ga, As + lin);
            GLL16(gb, Bs + lin);
        }
        __syncthreads();
#pragma unroll
        for (int ks = 0; ks < 2; ++ks) {
            s16x8 af[4], bf[4];
#pragma unroll
            for (int mi = 0; mi < 4; ++mi) {
                int row = wr * 64 + mi * 16 + fr;
                int off = (row << 7) + ((ks * 64 + g * 16) ^ ((row & 7) << 4));
                af[mi] = *(const s16x8*)(As + off);
            }
#pragma unroll
            for (int ni = 0; ni < 4; ++ni) {
                int row = wc * 64 + ni * 16 + fr;
                int off = (row << 7) + ((ks * 64 + g * 16) ^ ((row & 7) << 4));
                bf[ni] = *(const s16x8*)(Bs + off);
            }
#pragma unroll
            for (int mi = 0; mi < 4; ++mi)
#pragma unroll
                for (int ni = 0; ni < 4; ++ni)
                    acc[mi][ni] = __builtin_amdgcn_mfma_f32_16x16x32_bf16(
                        af[mi], bf[ni], acc[mi][ni], 0, 0, 0);
        }
        __syncthreads();
    }

    float bv[4];
#pragma unroll
    for (int ni = 0; ni < 4; ++ni) bv[ni] = bias[n0 + wc * 64 + ni * 16 + fr];
#pragma unroll
    for (int mi = 0; mi < 4; ++mi) {
#pragma unroll
        for (int r = 0; r < 4; ++r) {
            int row = m0 + wr * 64 + mi * 16 + g * 4 + r;
#pragma unroll
            for (int ni = 0; ni < 4; ++ni) {
                int col = n0 + wc * 64 + ni * 16 + fr;
                float v = acc[mi][ni][r] + bv[ni];
                if (RELU) v = v > 0.f ? v : 0.f;
                if (RESID) v += resid[(size_t)row * N + col];
                if (OUT_BF16)
                    ((unsigned short*)Cout)[(size_t)row * N + col] = f2bf(v);
                else
                    ((float*)Cout)[(size_t)row * N + col] = v;
            }
        }
    }
}

// ---------------------------------------------------------------------------
// gemm256 (r3 version, measured best for FFN1): 256x256, 8 waves, deep
// pipeline staged 2 tiles ahead, vmcnt(6)/(8) counted waits.
// ---------------------------------------------------------------------------
template <bool RELU, bool OUT_BF16>
__global__ __launch_bounds__(512, 2) void gemm256(
    const unsigned short* __restrict__ A, const unsigned short* __restrict__ Bw,
    const float* __restrict__ bias, void* __restrict__ Cout,
    int M, int N, int K) {
    extern __shared__ char lds[];

    const int tid = threadIdx.x;
    const int lane = tid & 63;
    const int w = tid >> 6;
    const int wm = w >> 2, wn = w & 3;
    const int g = lane >> 4, fr = lane & 15;

    const int nwg = gridDim.x * gridDim.y;
    const int L = blockIdx.y * gridDim.x + blockIdx.x;
    const int swz = (L & 7) * (nwg >> 3) + (L >> 3);
    const int m0 = (swz / gridDim.x) * 256;
    const int n0 = (swz % gridDim.x) * 256;

    const int NT = K >> 6;

    auto stageA = [&](int t, int h) {
        char* dst = lds + (t & 1) * 32768 + h * 16384;
#pragma unroll
        for (int c2 = 0; c2 < 2; ++c2) {
            int lin = (c2 * 512 + tid) * 16;
            int row = lin >> 7;
            int colb = (lin & 127) ^ ((row & 7) << 4);
            GLL16((const char*)A + ((size_t)(m0 + h * 128 + row) * K + t * 64) * 2 + colb,
                  dst + lin);
        }
    };
    auto stageB = [&](int t, int h) {
        char* dst = lds + 65536 + (t & 1) * 32768 + h * 16384;
#pragma unroll
        for (int c2 = 0; c2 < 2; ++c2) {
            int lin = (c2 * 512 + tid) * 16;
            int row = lin >> 7;
            int colb = (lin & 127) ^ ((row & 7) << 4);
            GLL16((const char*)Bw + ((size_t)(n0 + h * 128 + row) * K + t * 64) * 2 + colb,
                  dst + lin);
        }
    };

    f32x4 acc[2][4][2][2] = {};  // [ha][mi2][hb][ni2]
    s16x8 af[4][2];
    s16x8 bf[2][2];

    auto loadA = [&](const char* Ab, int ha) {
#pragma unroll
        for (int mi2 = 0; mi2 < 4; ++mi2) {
            int row = ha * 128 + wm * 64 + mi2 * 16 + fr;
#pragma unroll
            for (int ks = 0; ks < 2; ++ks)
                af[mi2][ks] = *(const s16x8*)(Ab + (row << 7) +
                               ((ks * 64 + g * 16) ^ ((row & 7) << 4)));
        }
    };
    auto loadB = [&](const char* Bb, int hb) {
#pragma unroll
        for (int ni2 = 0; ni2 < 2; ++ni2) {
            int row = hb * 128 + wn * 32 + ni2 * 16 + fr;
#pragma unroll
            for (int ks = 0; ks < 2; ++ks)
                bf[ni2][ks] = *(const s16x8*)(Bb + (row << 7) +
                               ((ks * 64 + g * 16) ^ ((row & 7) << 4)));
        }
    };

#define MFMAQ(HA, HB)                                                         \
    __builtin_amdgcn_s_barrier();                                             \
    asm volatile("s_waitcnt lgkmcnt(0)" ::: "memory");                        \
    __builtin_amdgcn_sched_barrier(0);                                        \
    __builtin_amdgcn_s_setprio(1);                                            \
    _Pragma("unroll")                                                         \
    for (int mi2 = 0; mi2 < 4; ++mi2)                                         \
        _Pragma("unroll")                                                     \
        for (int ni2 = 0; ni2 < 2; ++ni2)                                     \
            _Pragma("unroll")                                                 \
            for (int ks = 0; ks < 2; ++ks)                                    \
                acc[HA][mi2][HB][ni2] =                                       \
                    __builtin_amdgcn_mfma_f32_16x16x32_bf16(                  \
                        af[mi2][ks], bf[ni2][ks], acc[HA][mi2][HB][ni2],      \
                        0, 0, 0);                                             \
    __builtin_amdgcn_s_setprio(0);                                            \
    __builtin_amdgcn_s_barrier();

    stageA(0, 0); stageB(0, 0); stageA(0, 1); stageB(0, 1);
    stageA(1, 0); stageB(1, 0);
    VMC(8);
    __builtin_amdgcn_s_barrier();

    for (int t = 0; t < NT - 2; ++t) {
        char* Ab = lds + (t & 1) * 32768;
        char* Bb = lds + 65536 + (t & 1) * 32768;
        loadA(Ab, 0); loadB(Bb, 0); stageA(t + 1, 1); VMC(6); MFMAQ(0, 0);
        loadB(Bb, 1);               stageB(t + 1, 1);         MFMAQ(0, 1);
        loadA(Ab, 1); loadB(Bb, 0); stageA(t + 2, 0);         MFMAQ(1, 0);
        loadB(Bb, 1);               stageB(t + 2, 0); VMC(8); MFMAQ(1, 1);
    }
    {
        const int t = NT - 2;
        char* Ab = lds + (t & 1) * 32768;
        char* Bb = lds + 65536 + (t & 1) * 32768;
        loadA(Ab, 0); loadB(Bb, 0); stageA(t + 1, 1); VMC(6); MFMAQ(0, 0);
        loadB(Bb, 1);               stageB(t + 1, 1);         MFMAQ(0, 1);
        loadA(Ab, 1); loadB(Bb, 0);                           MFMAQ(1, 0);
        loadB(Bb, 1);                                 VMC(4); MFMAQ(1, 1);
    }
    {
        const int t = NT - 1;
        char* Ab = lds + (t & 1) * 32768;
        char* Bb = lds + 65536 + (t & 1) * 32768;
        loadA(Ab, 0); loadB(Bb, 0);                   VMC(0); MFMAQ(0, 0);
        loadB(Bb, 1);                                         MFMAQ(0, 1);
        loadA(Ab, 1); loadB(Bb, 0);                           MFMAQ(1, 0);
        loadB(Bb, 1);                                         MFMAQ(1, 1);
    }
#undef MFMAQ

#pragma unroll
    for (int ha = 0; ha < 2; ++ha)
#pragma unroll
        for (int mi2 = 0; mi2 < 4; ++mi2)
#pragma unroll
            for (int r = 0; r < 4; ++r) {
                int row = m0 + ha * 128 + wm * 64 + mi2 * 16 + g * 4 + r;
#pragma unroll
                for (int hb = 0; hb < 2; ++hb)
#pragma unroll
                    for (int ni2 = 0; ni2 < 2; ++ni2) {
                        int col = n0 + hb * 128 + wn * 32 + ni2 * 16 + fr;
                        float v = acc[ha][mi2][hb][ni2][r] + bias[col];
                        if (RELU) v = v > 0.f ? v : 0.f;
                        if (OUT_BF16)
                            ((unsigned short*)Cout)[(size_t)row * N + col] = f2bf(v);
                        else
                            ((float*)Cout)[(size_t)row * N + col] = v;
                    }
            }
}

// ---------------------------------------------------------------------------
// gemm_dp (r4 version, measured best for QKV round-quantization):
// BM=128, BN=256, 3-slot ring, staged 2 tiles ahead, vmcnt(6).
// ---------------------------------------------------------------------------
template <bool RELU, bool RESID, bool OUT_BF16>
__global__ __launch_bounds__(512, 2) void gemm_dp(
    const unsigned short* __restrict__ A, const unsigned short* __restrict__ Bw,
    const float* __restrict__ bias, const float* __restrict__ resid,
    void* __restrict__ Cout, int M, int N, int K) {
    extern __shared__ char lds[];

    const int tid = threadIdx.x;
    const int lane = tid & 63;
    const int w = tid >> 6;
    const int wm = w >> 2, wn = w & 3;   // 2M x 4N
    const int g = lane >> 4, fr = lane & 15;

    const int nwg = gridDim.x * gridDim.y;
    const int L = blockIdx.y * gridDim.x + blockIdx.x;
    const int swz = (L & 7) * (nwg >> 3) + (L >> 3);
    const int m0 = (swz / gridDim.x) * 128;
    const int n0 = (swz % gridDim.x) * 256;

    const int NT = K >> 6;

    auto stage = [&](int t) {
        char* dst = lds + (t % 3) * 49152;
#pragma unroll
        for (int c = 0; c < 2; ++c) {   // A: 128x64 bf16 = 16KB
            int lin = (c * 512 + tid) * 16;
            int row = lin >> 7;
            int colb = (lin & 127) ^ ((row & 7) << 4);
            GLL16((const char*)A + ((size_t)(m0 + row) * K + t * 64) * 2 + colb,
                  dst + lin);
        }
#pragma unroll
        for (int c = 0; c < 4; ++c) {   // B: 256x64 bf16 = 32KB
            int lin = (c * 512 + tid) * 16;
            int row = lin >> 7;
            int colb = (lin & 127) ^ ((row & 7) << 4);
            GLL16((const char*)Bw + ((size_t)(n0 + row) * K + t * 64) * 2 + colb,
                  dst + 16384 + lin);
        }
    };

    f32x4 acc[4][4] = {};   // [mi][ni]

    stage(0);
    stage(1);
    VMC(6);
    __builtin_amdgcn_s_barrier();

    for (int t = 0; t < NT; ++t) {
        char* Ab = lds + (t % 3) * 49152;
        char* Bb = Ab + 16384;
        s16x8 af[4][2], bf[4][2];
#pragma unroll
        for (int mi = 0; mi < 4; ++mi) {
            int row = wm * 64 + mi * 16 + fr;
#pragma unroll
            for (int ks = 0; ks < 2; ++ks)
                af[mi][ks] = *(const s16x8*)(Ab + (row << 7) +
                              ((ks * 64 + g * 16) ^ ((row & 7) << 4)));
        }
#pragma unroll
        for (int ni = 0; ni < 4; ++ni) {
            int row = wn * 64 + ni * 16 + fr;
#pragma unroll
            for (int ks = 0; ks < 2; ++ks)
                bf[ni][ks] = *(const s16x8*)(Bb + (row << 7) +
                              ((ks * 64 + g * 16) ^ ((row & 7) << 4)));
        }
        if (t + 2 < NT) { stage(t + 2); VMC(6); }
        else if (t + 1 < NT) { VMC(0); }
        __builtin_amdgcn_s_barrier();
        asm volatile("s_waitcnt lgkmcnt(0)" ::: "memory");
        __builtin_amdgcn_sched_barrier(0);
        __builtin_amdgcn_s_setprio(1);
#pragma unroll
        for (int mi = 0; mi < 4; ++mi)
#pragma unroll
            for (int ni = 0; ni < 4; ++ni)
#pragma unroll
                for (int ks = 0; ks < 2; ++ks)
                    acc[mi][ni] = __builtin_amdgcn_mfma_f32_16x16x32_bf16(
                        af[mi][ks], bf[ni][ks], acc[mi][ni], 0, 0, 0);
        __builtin_amdgcn_s_setprio(0);
        __builtin_amdgcn_s_barrier();
    }

    float bv[4];
#pragma unroll
    for (int ni = 0; ni < 4; ++ni) bv[ni] = bias[n0 + wn * 64 + ni * 16 + fr];
#pragma unroll
    for (int mi = 0; mi < 4; ++mi) {
#pragma unroll
        for (int r = 0; r < 4; ++r) {
            int row = m0 + wm * 64 + mi * 16 + g * 4 + r;
#pragma unroll
            for (int ni = 0; ni < 4; ++ni) {
                int col = n0 + wn * 64 + ni * 16 + fr;
                float v = acc[mi][ni][r] + bv[ni];
                if (RELU) v = v > 0.f ? v : 0.f;
                if (RESID) v += resid[(size_t)row * N + col];
                if (OUT_BF16)
                    ((unsigned short*)Cout)[(size_t)row * N + col] = f2bf(v);
                else
                    ((float*)Cout)[(size_t)row * N + col] = v;
            }
        }
    }
}

// ---------------------------------------------------------------------------
// Fused attention v3: round-1 structure + T14 async-STAGE split —
// V-loads + K-GLL for kt+1 issued BEFORE QK^T(kt) (MFMA hides latency);
// V scatter-write deferred to after softmax. Buffer hazards: buf^1 last
// read at PV(kt-1), synced by end-of-loop __syncthreads.
// ---------------------------------------------------------------------------
__global__ __launch_bounds__(512, 2) void attn_kernel(
    const unsigned short* __restrict__ qkv, const float* __restrict__ mask,
    unsigned short* __restrict__ ctx) {
    extern __shared__ char smem[];

    const int tid = threadIdx.x;
    const int lane = tid & 63;
    const int w = tid >> 6;
    const int l31 = lane & 31;
    const int hi = lane >> 5;
    const int bh = blockIdx.x >> 1;
    const int b = bh >> 4, h = bh & 15;
    const int qt = (blockIdx.x & 1) * 256 + w * 32;

    const size_t rstr = 3072;
    const unsigned short* qbase = qkv + (size_t)b * 512 * rstr + h * 64;
    const unsigned short* kbase = qbase + 1024;
    const unsigned short* vbase = qbase + 2048;
    const float* mrow = mask + b * 512;

    s16x8 qf[4];
#pragma unroll
    for (int kc = 0; kc < 4; ++kc)
        qf[kc] = *(const s16x8*)(qbase + (size_t)(qt + l31) * rstr + kc * 16 + hi * 8);

    f32x16 O0 = {}, O1 = {};
    float m = -3e38f, l = 0.f;
    const int bpbase = 36 * hi * 4;

    const int vs = tid & 127, vdg = tid >> 7;
    i32x4 vr0, vr1;   // in-flight V registers (T14 issue-early)

    auto issueV = [&](int kt) {
        const unsigned short* vsrc = vbase + (size_t)(kt * 128 + vs) * rstr + vdg * 16;
        vr0 = *(const i32x4*)vsrc;
        vr1 = *(const i32x4*)(vsrc + 8);
    };
    auto issueK = [&](int kt, int bufsel) {
        char* Kb = smem + bufsel * 16384;
#pragma unroll
        for (int c = 0; c < 2; ++c) {
            int lin = (c * 512 + tid) * 16;
            int row = lin >> 7;
            int colb = (lin & 127) ^ ((row & 7) << 4);
            GLL16((const char*)kbase + (size_t)(kt * 128 + row) * rstr * 2 + colb,
                  Kb + lin);
        }
    };
    auto writeV = [&](int bufsel) {   // consumes vr0/vr1 (compiler waits)
        char* Vb = smem + 32768 + bufsel * 16384;
        union { i32x4 v; unsigned short u[8]; } u0, u1;
        u0.v = vr0; u1.v = vr1;
#pragma unroll
        for (int j = 0; j < 8; ++j) {
            int d = vdg * 16 + j;
            *(unsigned short*)(Vb + d * 256 + ((vs * 2) ^ ((d & 15) << 4))) = u0.u[j];
        }
#pragma unroll
        for (int j = 0; j < 8; ++j) {
            int d = vdg * 16 + 8 + j;
            *(unsigned short*)(Vb + d * 256 + ((vs * 2) ^ ((d & 15) << 4))) = u1.u[j];
        }
    };

    const float C   = 0.18033688f;   // log2e / sqrt(64)
    const float L2E = 1.44269504f;

    issueV(0); issueK(0, 0);
    writeV(0);
    __syncthreads();

    for (int kt = 0; kt < 4; ++kt) {
        const int cur = kt & 1;
        if (kt < 3) { issueV(kt + 1); issueK(kt + 1, cur ^ 1); }
        char* Kb = smem + cur * 16384;
        char* Vb = smem + 32768 + cur * 16384;
        const int swzk = (l31 & 7) << 4;

        // ---- QK^T (hides the V/K loads just issued) ----
        f32x16 sc[4];
#pragma unroll
        for (int t = 0; t < 4; ++t) {
            f32x16 a = {};
#pragma unroll
            for (int kc = 0; kc < 4; ++kc) {
                s16x8 kf = *(const s16x8*)(Kb + (32 * t + l31) * 128 +
                                           ((kc * 32 + hi * 16) ^ swzk));
                a = __builtin_amdgcn_mfma_f32_32x32x16_bf16(kf, qf[kc], a, 0, 0, 0);
            }
            sc[t] = a;
        }

        float tm = -3e38f;
#pragma unroll
        for (int t = 0; t < 4; ++t) {
#pragma unroll
            for (int k2 = 0; k2 < 4; ++k2) {
                f32x4 mk = *(const f32x4*)(mrow + kt * 128 + 32 * t + 8 * k2 + 4 * hi);
#pragma unroll
                for (int i = 0; i < 4; ++i) {
                    float v = sc[t][4 * k2 + i] * C + mk[i] * L2E;
                    sc[t][4 * k2 + i] = v;
                    tm = fmaxf(tm, v);
                }
            }
        }
        tm = fmaxf(tm, __shfl_xor(tm, 32, 64));

        if (__any(tm > m + 11.0f)) {
            float mn = fmaxf(m, tm);
            float fac = exp2f(m - mn);
            m = mn;
            l *= fac;
            int fi = __float_as_int(fac);
#pragma unroll
            for (int r = 0; r < 16; ++r) {
                int q2 = (r & 3) + 8 * (r >> 2);
                float fq = __int_as_float(
                    __builtin_amdgcn_ds_bpermute(bpbase + q2 * 4, fi));
                O0[r] *= fq;
                O1[r] *= fq;
            }
        }

        float ts = 0.f;
#pragma unroll
        for (int t = 0; t < 4; ++t)
#pragma unroll
            for (int r = 0; r < 16; ++r) {
                float p = exp2f(sc[t][r] - m);
                sc[t][r] = p;
                ts += p;
            }
        ts += __shfl_xor(ts, 32, 64);
        l += ts;

        // ---- T14 write-late: scatter V(kt+1) into buf^1 ----
        if (kt < 3) writeV(cur ^ 1);

        unsigned pk01[4][4], pk23[4][4];
#pragma unroll
        for (int t = 0; t < 4; ++t)
#pragma unroll
            for (int k = 0; k < 4; ++k) {
                unsigned r0, r1;
                asm("v_cvt_pk_bf16_f32 %0, %1, %2"
                    : "=v"(r0) : "v"(sc[t][4 * k]), "v"(sc[t][4 * k + 1]));
                asm("v_cvt_pk_bf16_f32 %0, %1, %2"
                    : "=v"(r1) : "v"(sc[t][4 * k + 2]), "v"(sc[t][4 * k + 3]));
                pk01[t][k] = r0;
                pk23[t][k] = r1;
            }

#pragma unroll
        for (int t = 0; t < 4; ++t)
#pragma unroll
            for (int cc = 0; cc < 2; ++cc) {
                unsigned a0 = pk01[t][2 * cc], b0 = pk01[t][2 * cc + 1];
                unsigned c0 = pk23[t][2 * cc], d0 = pk23[t][2 * cc + 1];
                asm("v_permlane32_swap_b32 %0, %1" : "+v"(a0), "+v"(b0));
                asm("v_permlane32_swap_b32 %0, %1" : "+v"(c0), "+v"(d0));
                union { unsigned u[4]; s16x8 v; } pf;
                pf.u[0] = a0;
                pf.u[1] = c0;
                pf.u[2] = b0;
                pf.u[3] = d0;
                const int kc = 2 * t + cc;
                {
                    int row = l31;
                    s16x8 vf = *(const s16x8*)(Vb + row * 256 +
                               ((kc * 32 + hi * 16) ^ ((row & 15) << 4)));
                    O0 = __builtin_amdgcn_mfma_f32_32x32x16_bf16(pf.v, vf, O0, 0, 0, 0);
                }
                {
                    int row = 32 + l31;
                    s16x8 vf = *(const s16x8*)(Vb + row * 256 +
                               ((kc * 32 + hi * 16) ^ ((row & 15) << 4)));
                    O1 = __builtin_amdgcn_mfma_f32_32x32x16_bf16(pf.v, vf, O1, 0, 0, 0);
                }
            }
        __syncthreads();
    }

    const int li = __float_as_int(l);
#pragma unroll
    for (int r = 0; r < 16; ++r) {
        int q2 = (r & 3) + 8 * (r >> 2);
        float lq = __int_as_float(__builtin_amdgcn_ds_bpermute(bpbase + q2 * 4, li));
        float inv = 1.f / lq;
        size_t rowg = (size_t)(b * 512 + qt + q2 + 4 * hi) * 1024 + h * 64;
        ctx[rowg + l31]      = f2bf(O0[r] * inv);
        ctx[rowg + 32 + l31] = f2bf(O1[r] * inv);
    }
}

// ---------------------------------------------------------------------------
// Launch. ws layout (bytes): see round-0 comment (unchanged).
// ---------------------------------------------------------------------------
extern "C" void kernel_launch(void* const* d_in, const int* in_sizes, int n_in,
                              void* d_out, int out_size, void* d_ws, size_t ws_size,
                              hipStream_t stream) {
    const float* x    = (const float*)d_in[0];
    const float* mask = (const float*)d_in[1];
    const float* qkvw = (const float*)d_in[2];
    const float* qkvb = (const float*)d_in[3];
    const float* ow   = (const float*)d_in[4];
    const float* ob   = (const float*)d_in[5];
    const float* ln1g = (const float*)d_in[6];
    const float* ln1b = (const float*)d_in[7];
    const float* iw   = (const float*)d_in[8];
    const float* ib   = (const float*)d_in[9];
    const float* o2w  = (const float*)d_in[10];
    const float* o2b  = (const float*)d_in[11];
    const float* ln2g = (const float*)d_in[12];
    const float* ln2b = (const float*)d_in[13];

    char* ws = (char*)d_ws;
    unsigned short* qkvbuf = (unsigned short*)(ws);
    unsigned short* ybuf   = (unsigned short*)(ws + 50331648);
    unsigned short* cbuf   = (unsigned short*)(ws + 67108864);
    float*          x2     = (float*)(ws + 83886080);
    unsigned short* wq     = (unsigned short*)(ws + 117440512);
    unsigned short* wo     = (unsigned short*)(ws + 123731968);
    unsigned short* wi     = (unsigned short*)(ws + 125829120);
    unsigned short* wo2    = (unsigned short*)(ws + 134217728);
    unsigned short* hbuf   = (unsigned short*)(ws);  // overlays qkvbuf+ybuf

    hipFuncSetAttribute(reinterpret_cast<const void*>(attn_kernel),
                        hipFuncAttributeMaxDynamicSharedMemorySize, 65536);
    hipFuncSetAttribute(reinterpret_cast<const void*>(&gemm_dp<false, false, true>),
                        hipFuncAttributeMaxDynamicSharedMemorySize, 147456);
    hipFuncSetAttribute(reinterpret_cast<const void*>(&gemm256<true, true>),
                        hipFuncAttributeMaxDynamicSharedMemorySize, 131072);

    wconv_kernel<<<12288, 256, 0, stream>>>(qkvw, ow, iw, o2w, wq, wo, wi, wo2);
    ln_kernel<<<8192, 256, 0, stream>>>(x, ln1g, ln1b, ybuf);
    gemm_dp<false, false, true><<<dim3(12, 64), 512, 147456, stream>>>(
        ybuf, wq, qkvb, nullptr, qkvbuf, 8192, 3072, 1024);
    attn_kernel<<<512, 512, 65536, stream>>>(qkvbuf, mask, cbuf);
    gemm_bt<false, true, false><<<dim3(8, 64), 256, 0, stream>>>(
        cbuf, wo, ob, x, x2, 8192, 1024, 1024);
    ln_kernel<<<8192, 256, 0, stream>>>(x2, ln2g, ln2b, cbuf);
    gemm256<true, true><<<dim3(16, 32), 512, 131072, stream>>>(
        cbuf, wi, ib, hbuf, 8192, 4096, 1024);
    gemm_bt<false, true, false><<<dim3(8, 64), 256, 0, stream>>>(
        hbuf, wo2, o2b, x2, (float*)d_out, 8192, 1024, 4096);
}

// Round 7
// 291.947 us; speedup vs baseline: 1.1049x; 1.0465x over previous
//
#include <hip/hip_runtime.h>

// ---------------------------------------------------------------------------
// LSTransformerEncoderLayer on MI355X (gfx950), round 6.
// Round-6 changes:
//  (1) QKV -> gemm_bt (24,64)=1536 blocks @2/CU = 3 exact rounds (859 TF rate)
//  (2) x2 residual stored bf16 (proj out, LN2 in, FFN2 resid) — saves ~48MB
//      of HBM traffic across the chain.
// FFN1 = gemm256 (deep pipeline), proj/FFN2 = gemm_bt, attn = r5 (T14 split).
// ---------------------------------------------------------------------------

using f32x4  = __attribute__((ext_vector_type(4))) float;
using f32x16 = __attribute__((ext_vector_type(16))) float;
using s16x8  = __attribute__((ext_vector_type(8))) short;   // 8 bf16 in 4 VGPRs
using i32x4  = __attribute__((ext_vector_type(4))) int;

__device__ __forceinline__ unsigned short f2bf(float f) {
    unsigned x = __builtin_bit_cast(unsigned, f);
    return (unsigned short)((x + 0x7fffu + ((x >> 16) & 1u)) >> 16);  // RNE
}
__device__ __forceinline__ float bf2f(unsigned short u) {
    return __builtin_bit_cast(float, (unsigned)u << 16);
}

#define GLL16(gptr, lptr)                                                     \
    __builtin_amdgcn_global_load_lds(                                         \
        (const __attribute__((address_space(1))) void*)(gptr),                \
        (__attribute__((address_space(3))) void*)(lptr), 16, 0, 0)

#define VMC(N) asm volatile("s_waitcnt vmcnt(" #N ")" ::: "memory")

// ---------------------------------------------------------------------------
// Weight convert: fp32 -> bf16, all four weights in one launch.
// ---------------------------------------------------------------------------
__global__ __launch_bounds__(256) void wconv_kernel(
    const float* __restrict__ w0, const float* __restrict__ w1,
    const float* __restrict__ w2, const float* __restrict__ w3,
    unsigned short* __restrict__ o0, unsigned short* __restrict__ o1,
    unsigned short* __restrict__ o2, unsigned short* __restrict__ o3) {
    long idx = (long)blockIdx.x * 256 + threadIdx.x;  // float4 index
    const float* src;
    unsigned short* dst;
    long rel;
    if (idx < 786432L)        { src = w0; dst = o0; rel = idx; }
    else if (idx < 1048576L)  { src = w1; dst = o1; rel = idx - 786432L; }
    else if (idx < 2097152L)  { src = w2; dst = o2; rel = idx - 1048576L; }
    else                      { src = w3; dst = o3; rel = idx - 2097152L; }
    float4 v = *(const float4*)(src + rel * 4);
    ushort4 o;
    o.x = f2bf(v.x); o.y = f2bf(v.y); o.z = f2bf(v.z); o.w = f2bf(v.w);
    *(ushort4*)(dst + rel * 4) = o;
}

// ---------------------------------------------------------------------------
// LayerNorm: one block per row of 1024, 256 threads. IN_BF16 selects input.
// ---------------------------------------------------------------------------
template <bool IN_BF16>
__global__ __launch_bounds__(256) void ln_kernel(
    const void* __restrict__ xin, const float* __restrict__ gw,
    const float* __restrict__ bw, unsigned short* __restrict__ y) {
    __shared__ float rbuf[8];
    const int row = blockIdx.x;
    const int t = threadIdx.x;
    float4 v;
    if (IN_BF16) {
        ushort4 u = *(const ushort4*)((const unsigned short*)xin +
                                      (size_t)row * 1024 + t * 4);
        v.x = bf2f(u.x); v.y = bf2f(u.y); v.z = bf2f(u.z); v.w = bf2f(u.w);
    } else {
        v = *(const float4*)((const float*)xin + (size_t)row * 1024 + t * 4);
    }
    float s  = v.x + v.y + v.z + v.w;
    float ss = v.x * v.x + v.y * v.y + v.z * v.z + v.w * v.w;
#pragma unroll
    for (int sh = 1; sh < 64; sh <<= 1) {
        s  += __shfl_xor(s, sh, 64);
        ss += __shfl_xor(ss, sh, 64);
    }
    int w = t >> 6;
    if ((t & 63) == 0) { rbuf[w * 2] = s; rbuf[w * 2 + 1] = ss; }
    __syncthreads();
    s  = rbuf[0] + rbuf[2] + rbuf[4] + rbuf[6];
    ss = rbuf[1] + rbuf[3] + rbuf[5] + rbuf[7];
    float mu  = s * (1.f / 1024.f);
    float var = ss * (1.f / 1024.f) - mu * mu;
    float rs  = rsqrtf(var + 1e-5f);
    float4 gv = *(const float4*)(gw + t * 4);
    float4 bv = *(const float4*)(bw + t * 4);
    ushort4 o;
    o.x = f2bf((v.x - mu) * rs * gv.x + bv.x);
    o.y = f2bf((v.y - mu) * rs * gv.y + bv.y);
    o.z = f2bf((v.z - mu) * rs * gv.z + bv.z);
    o.w = f2bf((v.w - mu) * rs * gv.w + bv.w);
    *(ushort4*)(y + (size_t)row * 1024 + t * 4) = o;
}

// ---------------------------------------------------------------------------
// gemm_bt (m97 2-barrier structure) + T1 XCD swizzle. QKV, proj, FFN2.
// resid may be f32 or bf16 (RESID_BF16).
// ---------------------------------------------------------------------------
template <bool RELU, bool RESID, bool RESID_BF16, bool OUT_BF16>
__global__ __launch_bounds__(256, 2) void gemm_bt(
    const unsigned short* __restrict__ A, const unsigned short* __restrict__ Bw,
    const float* __restrict__ bias, const void* __restrict__ resid,
    void* __restrict__ Cout, int M, int N, int K) {
    __shared__ char smem[2 * 128 * 64 * 2];
    char* As = smem;
    char* Bs = smem + 128 * 64 * 2;

    const int tid = threadIdx.x;
    const int lane = tid & 63;
    const int w = tid >> 6;
    const int wr = w >> 1, wc = w & 1;
    const int g = lane >> 4;
    const int fr = lane & 15;
    const int nwg = gridDim.x * gridDim.y;
    const int L = blockIdx.y * gridDim.x + blockIdx.x;
    const int swz = (L & 7) * (nwg >> 3) + (L >> 3);
    const int m0 = (swz / gridDim.x) * 128;
    const int n0 = (swz % gridDim.x) * 128;

    f32x4 acc[4][4] = {};

    for (int kt = 0; kt < K; kt += 64) {
#pragma unroll
        for (int c = 0; c < 4; ++c) {
            int lin = (c * 256 + tid) * 16;
            int row = lin >> 7;
            int Lb = lin ^ ((row & 7) << 4);
            int colb = Lb & 127;
            const char* ga = (const char*)A + ((size_t)(m0 + row) * K + kt) * 2 + colb;
            const char* gb = (const char*)Bw + ((size_t)(n0 + row) * K + kt) * 2 + colb;
            GLL16(ga, As + lin);
            GLL16(gb, Bs + lin);
        }
        __syncthreads();
#pragma unroll
        for (int ks = 0; ks < 2; ++ks) {
            s16x8 af[4], bf[4];
#pragma unroll
            for (int mi = 0; mi < 4; ++mi) {
                int row = wr * 64 + mi * 16 + fr;
                int off = (row << 7) + ((ks * 64 + g * 16) ^ ((row & 7) << 4));
                af[mi] = *(const s16x8*)(As + off);
            }
#pragma unroll
            for (int ni = 0; ni < 4; ++ni) {
                int row = wc * 64 + ni * 16 + fr;
                int off = (row << 7) + ((ks * 64 + g * 16) ^ ((row & 7) << 4));
                bf[ni] = *(const s16x8*)(Bs + off);
            }
#pragma unroll
            for (int mi = 0; mi < 4; ++mi)
#pragma unroll
                for (int ni = 0; ni < 4; ++ni)
                    acc[mi][ni] = __builtin_amdgcn_mfma_f32_16x16x32_bf16(
                        af[mi], bf[ni], acc[mi][ni], 0, 0, 0);
        }
        __syncthreads();
    }

    float bv[4];
#pragma unroll
    for (int ni = 0; ni < 4; ++ni) bv[ni] = bias[n0 + wc * 64 + ni * 16 + fr];
#pragma unroll
    for (int mi = 0; mi < 4; ++mi) {
#pragma unroll
        for (int r = 0; r < 4; ++r) {
            int row = m0 + wr * 64 + mi * 16 + g * 4 + r;
#pragma unroll
            for (int ni = 0; ni < 4; ++ni) {
                int col = n0 + wc * 64 + ni * 16 + fr;
                float v = acc[mi][ni][r] + bv[ni];
                if (RELU) v = v > 0.f ? v : 0.f;
                if (RESID) {
                    size_t ri = (size_t)row * N + col;
                    v += RESID_BF16 ? bf2f(((const unsigned short*)resid)[ri])
                                    : ((const float*)resid)[ri];
                }
                if (OUT_BF16)
                    ((unsigned short*)Cout)[(size_t)row * N + col] = f2bf(v);
                else
                    ((float*)Cout)[(size_t)row * N + col] = v;
            }
        }
    }
}

// ---------------------------------------------------------------------------
// gemm256 (r3 version, measured best for FFN1): 256x256, 8 waves, deep
// pipeline staged 2 tiles ahead, vmcnt(6)/(8) counted waits.
// ---------------------------------------------------------------------------
template <bool RELU, bool OUT_BF16>
__global__ __launch_bounds__(512, 2) void gemm256(
    const unsigned short* __restrict__ A, const unsigned short* __restrict__ Bw,
    const float* __restrict__ bias, void* __restrict__ Cout,
    int M, int N, int K) {
    extern __shared__ char lds[];

    const int tid = threadIdx.x;
    const int lane = tid & 63;
    const int w = tid >> 6;
    const int wm = w >> 2, wn = w & 3;
    const int g = lane >> 4, fr = lane & 15;

    const int nwg = gridDim.x * gridDim.y;
    const int L = blockIdx.y * gridDim.x + blockIdx.x;
    const int swz = (L & 7) * (nwg >> 3) + (L >> 3);
    const int m0 = (swz / gridDim.x) * 256;
    const int n0 = (swz % gridDim.x) * 256;

    const int NT = K >> 6;

    auto stageA = [&](int t, int h) {
        char* dst = lds + (t & 1) * 32768 + h * 16384;
#pragma unroll
        for (int c2 = 0; c2 < 2; ++c2) {
            int lin = (c2 * 512 + tid) * 16;
            int row = lin >> 7;
            int colb = (lin & 127) ^ ((row & 7) << 4);
            GLL16((const char*)A + ((size_t)(m0 + h * 128 + row) * K + t * 64) * 2 + colb,
                  dst + lin);
        }
    };
    auto stageB = [&](int t, int h) {
        char* dst = lds + 65536 + (t & 1) * 32768 + h * 16384;
#pragma unroll
        for (int c2 = 0; c2 < 2; ++c2) {
            int lin = (c2 * 512 + tid) * 16;
            int row = lin >> 7;
            int colb = (lin & 127) ^ ((row & 7) << 4);
            GLL16((const char*)Bw + ((size_t)(n0 + h * 128 + row) * K + t * 64) * 2 + colb,
                  dst + lin);
        }
    };

    f32x4 acc[2][4][2][2] = {};  // [ha][mi2][hb][ni2]
    s16x8 af[4][2];
    s16x8 bf[2][2];

    auto loadA = [&](const char* Ab, int ha) {
#pragma unroll
        for (int mi2 = 0; mi2 < 4; ++mi2) {
            int row = ha * 128 + wm * 64 + mi2 * 16 + fr;
#pragma unroll
            for (int ks = 0; ks < 2; ++ks)
                af[mi2][ks] = *(const s16x8*)(Ab + (row << 7) +
                               ((ks * 64 + g * 16) ^ ((row & 7) << 4)));
        }
    };
    auto loadB = [&](const char* Bb, int hb) {
#pragma unroll
        for (int ni2 = 0; ni2 < 2; ++ni2) {
            int row = hb * 128 + wn * 32 + ni2 * 16 + fr;
#pragma unroll
            for (int ks = 0; ks < 2; ++ks)
                bf[ni2][ks] = *(const s16x8*)(Bb + (row << 7) +
                               ((ks * 64 + g * 16) ^ ((row & 7) << 4)));
        }
    };

#define MFMAQ(HA, HB)                                                         \
    __builtin_amdgcn_s_barrier();                                             \
    asm volatile("s_waitcnt lgkmcnt(0)" ::: "memory");                        \
    __builtin_amdgcn_sched_barrier(0);                                        \
    __builtin_amdgcn_s_setprio(1);                                            \
    _Pragma("unroll")                                                         \
    for (int mi2 = 0; mi2 < 4; ++mi2)                                         \
        _Pragma("unroll")                                                     \
        for (int ni2 = 0; ni2 < 2; ++ni2)                                     \
            _Pragma("unroll")                                                 \
            for (int ks = 0; ks < 2; ++ks)                                    \
                acc[HA][mi2][HB][ni2] =                                       \
                    __builtin_amdgcn_mfma_f32_16x16x32_bf16(                  \
                        af[mi2][ks], bf[ni2][ks], acc[HA][mi2][HB][ni2],      \
                        0, 0, 0);                                             \
    __builtin_amdgcn_s_setprio(0);                                            \
    __builtin_amdgcn_s_barrier();

    stageA(0, 0); stageB(0, 0); stageA(0, 1); stageB(0, 1);
    stageA(1, 0); stageB(1, 0);
    VMC(8);
    __builtin_amdgcn_s_barrier();

    for (int t = 0; t < NT - 2; ++t) {
        char* Ab = lds + (t & 1) * 32768;
        char* Bb = lds + 65536 + (t & 1) * 32768;
        loadA(Ab, 0); loadB(Bb, 0); stageA(t + 1, 1); VMC(6); MFMAQ(0, 0);
        loadB(Bb, 1);               stageB(t + 1, 1);         MFMAQ(0, 1);
        loadA(Ab, 1); loadB(Bb, 0); stageA(t + 2, 0);         MFMAQ(1, 0);
        loadB(Bb, 1);               stageB(t + 2, 0); VMC(8); MFMAQ(1, 1);
    }
    {
        const int t = NT - 2;
        char* Ab = lds + (t & 1) * 32768;
        char* Bb = lds + 65536 + (t & 1) * 32768;
        loadA(Ab, 0); loadB(Bb, 0); stageA(t + 1, 1); VMC(6); MFMAQ(0, 0);
        loadB(Bb, 1);               stageB(t + 1, 1);         MFMAQ(0, 1);
        loadA(Ab, 1); loadB(Bb, 0);                           MFMAQ(1, 0);
        loadB(Bb, 1);                                 VMC(4); MFMAQ(1, 1);
    }
    {
        const int t = NT - 1;
        char* Ab = lds + (t & 1) * 32768;
        char* Bb = lds + 65536 + (t & 1) * 32768;
        loadA(Ab, 0); loadB(Bb, 0);                   VMC(0); MFMAQ(0, 0);
        loadB(Bb, 1);                                         MFMAQ(0, 1);
        loadA(Ab, 1); loadB(Bb, 0);                           MFMAQ(1, 0);
        loadB(Bb, 1);                                         MFMAQ(1, 1);
    }
#undef MFMAQ

#pragma unroll
    for (int ha = 0; ha < 2; ++ha)
#pragma unroll
        for (int mi2 = 0; mi2 < 4; ++mi2)
#pragma unroll
            for (int r = 0; r < 4; ++r) {
                int row = m0 + ha * 128 + wm * 64 + mi2 * 16 + g * 4 + r;
#pragma unroll
                for (int hb = 0; hb < 2; ++hb)
#pragma unroll
                    for (int ni2 = 0; ni2 < 2; ++ni2) {
                        int col = n0 + hb * 128 + wn * 32 + ni2 * 16 + fr;
                        float v = acc[ha][mi2][hb][ni2][r] + bias[col];
                        if (RELU) v = v > 0.f ? v : 0.f;
                        if (OUT_BF16)
                            ((unsigned short*)Cout)[(size_t)row * N + col] = f2bf(v);
                        else
                            ((float*)Cout)[(size_t)row * N + col] = v;
                    }
            }
}

// ---------------------------------------------------------------------------
// Fused attention v3 (r5 version: T14 async-STAGE split).
// ---------------------------------------------------------------------------
__global__ __launch_bounds__(512, 2) void attn_kernel(
    const unsigned short* __restrict__ qkv, const float* __restrict__ mask,
    unsigned short* __restrict__ ctx) {
    extern __shared__ char smem[];

    const int tid = threadIdx.x;
    const int lane = tid & 63;
    const int w = tid >> 6;
    const int l31 = lane & 31;
    const int hi = lane >> 5;
    const int bh = blockIdx.x >> 1;
    const int b = bh >> 4, h = bh & 15;
    const int qt = (blockIdx.x & 1) * 256 + w * 32;

    const size_t rstr = 3072;
    const unsigned short* qbase = qkv + (size_t)b * 512 * rstr + h * 64;
    const unsigned short* kbase = qbase + 1024;
    const unsigned short* vbase = qbase + 2048;
    const float* mrow = mask + b * 512;

    s16x8 qf[4];
#pragma unroll
    for (int kc = 0; kc < 4; ++kc)
        qf[kc] = *(const s16x8*)(qbase + (size_t)(qt + l31) * rstr + kc * 16 + hi * 8);

    f32x16 O0 = {}, O1 = {};
    float m = -3e38f, l = 0.f;
    const int bpbase = 36 * hi * 4;

    const int vs = tid & 127, vdg = tid >> 7;
    i32x4 vr0, vr1;   // in-flight V registers (T14 issue-early)

    auto issueV = [&](int kt) {
        const unsigned short* vsrc = vbase + (size_t)(kt * 128 + vs) * rstr + vdg * 16;
        vr0 = *(const i32x4*)vsrc;
        vr1 = *(const i32x4*)(vsrc + 8);
    };
    auto issueK = [&](int kt, int bufsel) {
        char* Kb = smem + bufsel * 16384;
#pragma unroll
        for (int c = 0; c < 2; ++c) {
            int lin = (c * 512 + tid) * 16;
            int row = lin >> 7;
            int colb = (lin & 127) ^ ((row & 7) << 4);
            GLL16((const char*)kbase + (size_t)(kt * 128 + row) * rstr * 2 + colb,
                  Kb + lin);
        }
    };
    auto writeV = [&](int bufsel) {
        char* Vb = smem + 32768 + bufsel * 16384;
        union { i32x4 v; unsigned short u[8]; } u0, u1;
        u0.v = vr0; u1.v = vr1;
#pragma unroll
        for (int j = 0; j < 8; ++j) {
            int d = vdg * 16 + j;
            *(unsigned short*)(Vb + d * 256 + ((vs * 2) ^ ((d & 15) << 4))) = u0.u[j];
        }
#pragma unroll
        for (int j = 0; j < 8; ++j) {
            int d = vdg * 16 + 8 + j;
            *(unsigned short*)(Vb + d * 256 + ((vs * 2) ^ ((d & 15) << 4))) = u1.u[j];
        }
    };

    const float C   = 0.18033688f;   // log2e / sqrt(64)
    const float L2E = 1.44269504f;

    issueV(0); issueK(0, 0);
    writeV(0);
    __syncthreads();

    for (int kt = 0; kt < 4; ++kt) {
        const int cur = kt & 1;
        if (kt < 3) { issueV(kt + 1); issueK(kt + 1, cur ^ 1); }
        char* Kb = smem + cur * 16384;
        char* Vb = smem + 32768 + cur * 16384;
        const int swzk = (l31 & 7) << 4;

        f32x16 sc[4];
#pragma unroll
        for (int t = 0; t < 4; ++t) {
            f32x16 a = {};
#pragma unroll
            for (int kc = 0; kc < 4; ++kc) {
                s16x8 kf = *(const s16x8*)(Kb + (32 * t + l31) * 128 +
                                           ((kc * 32 + hi * 16) ^ swzk));
                a = __builtin_amdgcn_mfma_f32_32x32x16_bf16(kf, qf[kc], a, 0, 0, 0);
            }
            sc[t] = a;
        }

        float tm = -3e38f;
#pragma unroll
        for (int t = 0; t < 4; ++t) {
#pragma unroll
            for (int k2 = 0; k2 < 4; ++k2) {
                f32x4 mk = *(const f32x4*)(mrow + kt * 128 + 32 * t + 8 * k2 + 4 * hi);
#pragma unroll
                for (int i = 0; i < 4; ++i) {
                    float v = sc[t][4 * k2 + i] * C + mk[i] * L2E;
                    sc[t][4 * k2 + i] = v;
                    tm = fmaxf(tm, v);
                }
            }
        }
        tm = fmaxf(tm, __shfl_xor(tm, 32, 64));

        if (__any(tm > m + 11.0f)) {
            float mn = fmaxf(m, tm);
            float fac = exp2f(m - mn);
            m = mn;
            l *= fac;
            int fi = __float_as_int(fac);
#pragma unroll
            for (int r = 0; r < 16; ++r) {
                int q2 = (r & 3) + 8 * (r >> 2);
                float fq = __int_as_float(
                    __builtin_amdgcn_ds_bpermute(bpbase + q2 * 4, fi));
                O0[r] *= fq;
                O1[r] *= fq;
            }
        }

        float ts = 0.f;
#pragma unroll
        for (int t = 0; t < 4; ++t)
#pragma unroll
            for (int r = 0; r < 16; ++r) {
                float p = exp2f(sc[t][r] - m);
                sc[t][r] = p;
                ts += p;
            }
        ts += __shfl_xor(ts, 32, 64);
        l += ts;

        if (kt < 3) writeV(cur ^ 1);

        unsigned pk01[4][4], pk23[4][4];
#pragma unroll
        for (int t = 0; t < 4; ++t)
#pragma unroll
            for (int k = 0; k < 4; ++k) {
                unsigned r0, r1;
                asm("v_cvt_pk_bf16_f32 %0, %1, %2"
                    : "=v"(r0) : "v"(sc[t][4 * k]), "v"(sc[t][4 * k + 1]));
                asm("v_cvt_pk_bf16_f32 %0, %1, %2"
                    : "=v"(r1) : "v"(sc[t][4 * k + 2]), "v"(sc[t][4 * k + 3]));
                pk01[t][k] = r0;
                pk23[t][k] = r1;
            }

#pragma unroll
        for (int t = 0; t < 4; ++t)
#pragma unroll
            for (int cc = 0; cc < 2; ++cc) {
                unsigned a0 = pk01[t][2 * cc], b0 = pk01[t][2 * cc + 1];
                unsigned c0 = pk23[t][2 * cc], d0 = pk23[t][2 * cc + 1];
                asm("v_permlane32_swap_b32 %0, %1" : "+v"(a0), "+v"(b0));
                asm("v_permlane32_swap_b32 %0, %1" : "+v"(c0), "+v"(d0));
                union { unsigned u[4]; s16x8 v; } pf;
                pf.u[0] = a0;
                pf.u[1] = c0;
                pf.u[2] = b0;
                pf.u[3] = d0;
                const int kc = 2 * t + cc;
                {
                    int row = l31;
                    s16x8 vf = *(const s16x8*)(Vb + row * 256 +
                               ((kc * 32 + hi * 16) ^ ((row & 15) << 4)));
                    O0 = __builtin_amdgcn_mfma_f32_32x32x16_bf16(pf.v, vf, O0, 0, 0, 0);
                }
                {
                    int row = 32 + l31;
                    s16x8 vf = *(const s16x8*)(Vb + row * 256 +
                               ((kc * 32 + hi * 16) ^ ((row & 15) << 4)));
                    O1 = __builtin_amdgcn_mfma_f32_32x32x16_bf16(pf.v, vf, O1, 0, 0, 0);
                }
            }
        __syncthreads();
    }

    const int li = __float_as_int(l);
#pragma unroll
    for (int r = 0; r < 16; ++r) {
        int q2 = (r & 3) + 8 * (r >> 2);
        float lq = __int_as_float(__builtin_amdgcn_ds_bpermute(bpbase + q2 * 4, li));
        float inv = 1.f / lq;
        size_t rowg = (size_t)(b * 512 + qt + q2 + 4 * hi) * 1024 + h * 64;
        ctx[rowg + l31]      = f2bf(O0[r] * inv);
        ctx[rowg + 32 + l31] = f2bf(O1[r] * inv);
    }
}

// ---------------------------------------------------------------------------
// Launch. ws layout (bytes):
//   0          qkv bf16   [8192][3072]  50,331,648   (later overlaid by h)
//   50331648   y1 bf16    [8192][1024]  16,777,216
//   67108864   ctx/y2 bf16[8192][1024]  16,777,216
//   83886080   x2 bf16    [8192][1024]  16,777,216   (was f32)
//   117440512  bf16 weights (qkv_w, attn_ow, inter_w, out_w) 25,165,824
// ---------------------------------------------------------------------------
extern "C" void kernel_launch(void* const* d_in, const int* in_sizes, int n_in,
                              void* d_out, int out_size, void* d_ws, size_t ws_size,
                              hipStream_t stream) {
    const float* x    = (const float*)d_in[0];
    const float* mask = (const float*)d_in[1];
    const float* qkvw = (const float*)d_in[2];
    const float* qkvb = (const float*)d_in[3];
    const float* ow   = (const float*)d_in[4];
    const float* ob   = (const float*)d_in[5];
    const float* ln1g = (const float*)d_in[6];
    const float* ln1b = (const float*)d_in[7];
    const float* iw   = (const float*)d_in[8];
    const float* ib   = (const float*)d_in[9];
    const float* o2w  = (const float*)d_in[10];
    const float* o2b  = (const float*)d_in[11];
    const float* ln2g = (const float*)d_in[12];
    const float* ln2b = (const float*)d_in[13];

    char* ws = (char*)d_ws;
    unsigned short* qkvbuf = (unsigned short*)(ws);
    unsigned short* ybuf   = (unsigned short*)(ws + 50331648);
    unsigned short* cbuf   = (unsigned short*)(ws + 67108864);
    unsigned short* x2bf   = (unsigned short*)(ws + 83886080);
    unsigned short* wq     = (unsigned short*)(ws + 117440512);
    unsigned short* wo     = (unsigned short*)(ws + 123731968);
    unsigned short* wi     = (unsigned short*)(ws + 125829120);
    unsigned short* wo2    = (unsigned short*)(ws + 134217728);
    unsigned short* hbuf   = (unsigned short*)(ws);  // overlays qkvbuf+ybuf

    hipFuncSetAttribute(reinterpret_cast<const void*>(attn_kernel),
                        hipFuncAttributeMaxDynamicSharedMemorySize, 65536);
    hipFuncSetAttribute(reinterpret_cast<const void*>(&gemm256<true, true>),
                        hipFuncAttributeMaxDynamicSharedMemorySize, 131072);

    wconv_kernel<<<12288, 256, 0, stream>>>(qkvw, ow, iw, o2w, wq, wo, wi, wo2);
    ln_kernel<false><<<8192, 256, 0, stream>>>(x, ln1g, ln1b, ybuf);
    gemm_bt<false, false, false, true><<<dim3(24, 64), 256, 0, stream>>>(
        ybuf, wq, qkvb, nullptr, qkvbuf, 8192, 3072, 1024);
    attn_kernel<<<512, 512, 65536, stream>>>(qkvbuf, mask, cbuf);
    gemm_bt<false, true, false, true><<<dim3(8, 64), 256, 0, stream>>>(
        cbuf, wo, ob, x, x2bf, 8192, 1024, 1024);
    ln_kernel<true><<<8192, 256, 0, stream>>>(x2bf, ln2g, ln2b, cbuf);
    gemm256<true, true><<<dim3(16, 32), 512, 131072, stream>>>(
        cbuf, wi, ib, hbuf, 8192, 4096, 1024);
    gemm_bt<false, true, true, false><<<dim3(8, 64), 256, 0, stream>>>(
        hbuf, wo2, o2b, x2bf, (float*)d_out, 8192, 1024, 4096);
}